// Round 13
// baseline (156.924 us; speedup 1.0000x reference)
//
#include <hip/hip_runtime.h>

// Problem: BATCH=64, NFILT=512, T=1024, FFT over first 512 samples, 257 bins.
//   bc = (fc/Q)*0.5*sqrt(2pi)/FS ; n = t+1
//   y[b,f,t] = exp(-(bc*n)^2) * cos(2pi*fc/FS*n)
//   maxsq[f] = max_{b,k} |DFT_512(y[b,f,0:512])[k]|^2
//   out[b,f,t] = y[b,f,1023-t] * rsqrt(maxsq[f])
//
// R23 = R22 byte-identical resubmission (Round-12 bench died with
//   GPUAcquisitionTimeout — broker capacity, same as Round 0; kernel never
//   ran. No evidence against R22's design.)
//
// R22: consolidated-resident compute (probe-shaped), two plain kernels.
//   Evidence: R17 probe ran the FULL compute pass at 22.2us/rep when work
//   was consolidated in resident blocks (8 reps amortize ramp/drain);
//   standalone k_maxfft accounts for ~30-35us under C~99.
//   => run compute as 2048 blocks (exactly one resident cohort at 8
//   blocks/CU) x 4 waves x 4 signals/wave, eliminating cohort churn.
//   - mapping (bijection, f block-uniform per slot):
//     g=blk>>2, c=blk&3; slot k: f=(g+128k)&511, bb=16k+4c+w.
//     inverse: k=bb>>4, c=(bb>>2)&3, w=bb&3, g=(f-128k)&511 => bijection.
//     Heavy filters (f<46) land in <=1 slot per wave => balanced.
//   - per-signal math EXACT R12 (gen -> windowed Goertzel -> 64-lane
//     reduce; pruned -> 0.0). Q columns staged once per block (4 cols,
//     1 load/thread) like R19.
//   - k_write: byte-identical R12 (17.05us @ 7.9 TB/s, 98% peak, R16).
//   __launch_bounds__(256,8): VGPR<=64 so 8 blocks/CU co-reside.
//   Prediction: C~100 => 140-146us; C~112+ => neutral => declare roofline
//   next round. absmax must stay EXACTLY 0.0009765625.

#define BCOEF_K 7.8332133582218756e-05f  // 0.5*sqrt(2*pi)/16000
#define INV_FS  6.25e-05f                // 1/16000
#define TWO_PI  6.28318530717958647692f
#define PI_F    3.14159265358979323846f
#define SIGK_K  115.2309f                // sqrt(2)*512/(2*pi)
#define KAPPA   1.3f                     // pruning safety factor
#define FULL_FC 700.0f                   // below this fc, evaluate all 64 b

typedef float vf4 __attribute__((ext_vector_type(4)));

__device__ __forceinline__ float fast_carrier(float fcn, float n) {
  float rev = fcn * n;
  float fr  = rev - floorf(rev);
  return __cosf(TWO_PI * fr);
}
__device__ __forceinline__ float fast_env(float x) { return __expf(-x * x); }

// ---------------------------------------------------------------------------
// Kernel 1 (R22): 2048 blocks x 4 waves; wave runs 4 signals (slots k=0..3),
// f block-uniform per slot. Per-signal body is exactly R12's.
// ---------------------------------------------------------------------------
__global__ __launch_bounds__(256, 8) void k_maxfft3(const float* __restrict__ Q,
                                                    const float* __restrict__ fc,
                                                    float* __restrict__ ws) {
  const int tid  = threadIdx.x;
  const int w    = tid >> 6;           // wave 0..3
  const int lane = tid & 63;
  const int b    = blockIdx.x;
  const int c    = b & 3;              // bb-chunk selector
  const int g    = b >> 2;             // filter base 0..511

  __shared__ __align__(16) float ybuf[4][512];
  __shared__ float qcol4[4][64];       // Q columns for this block's 4 filters

  // stage the 4 Q columns: one load per thread (same total gather as R19)
  {
    const int kk = tid >> 6;                         // 0..3
    const int bi = tid & 63;                         // batch index
    const int fk = (g + kk * 128) & 511;
    qcol4[kk][bi] = Q[bi * 512 + fk];
  }
  __syncthreads();

  float* const yw = &ybuf[w][0];                     // wave-private LDS row
  const float4* const y4 = (const float4*)yw;

  for (int k = 0; k < 4; ++k) {
    const int f  = (g + k * 128) & 511;
    const int bb = k * 16 + c * 4 + w;

    const float fcv = fc[f];
    const float fcn = fcv * INV_FS;
    const float qv  = qcol4[k][bb];
    const float bc  = (fcv / qv) * BCOEF_K;

    // pruning predicate (same values, same shfl tree as R12)
    float qq = qcol4[k][lane];
    #pragma unroll
    for (int d = 32; d > 0; d >>= 1) qq = fmaxf(qq, __shfl_xor(qq, d));
    if (fcv >= FULL_FC && bc * qq > KAPPA * fcv * BCOEF_K) {
      if (lane == 0) ws[f * 64 + bb] = 0.0f;         // same as R12's zeros
      continue;                                       // wave-uniform
    }

    // effective length: env < e^-16 beyond nstar = 4/bc (wave-uniform)
    const float nstar = 4.0f / bc;
    const int   N_eff = (nstar >= 510.0f) ? 512 : ((int)nstar + 2);
    const int   jmax  = (N_eff + 3) >> 2;            // float4 Goertzel groups
    const int   n4    = jmax << 2;                   // samples to generate

    // prior slot's LDS reads must drain before overwrite (wave-local)
    asm volatile("s_waitcnt lgkmcnt(0)" ::: "memory");

    // lane-strided generation
    const int nit_g = (n4 + 63) >> 6;                // 1..8, wave-uniform
    for (int r = 0; r < nit_g; ++r) {
      const int idx = (r << 6) + lane;               // t index; n = idx+1
      const float n = (float)(idx + 1);
      const float v = fast_env(bc * n) * fast_carrier(fcn, n);
      if (idx < n4) yw[idx] = v;                     // masked tail store
    }
    asm volatile("s_waitcnt lgkmcnt(0)" ::: "memory");

    // spectral-peak window (wave-uniform)
    const int kci  = (int)(fcn * 512.0f + 0.5f);
    const int W    = (int)(2.0f * (bc * SIGK_K)) + 6;
    const int k_lo = max(0, kci - W);
    const int k_hi = min(256, kci + W);
    const int nit  = ((k_hi - k_lo) >> 6) + 1;       // 1..5 iterations

    float mx = 0.0f;
    for (int it = 0; it < nit; ++it) {               // wave-uniform trips
      const int   kb = min(k_lo + (it << 6) + lane, k_hi);  // dup harmless
      const float cc = 2.0f * cosf((float)kb * (PI_F / 256.0f));
      float s1 = 0.0f, s2 = 0.0f;
      #pragma unroll 4
      for (int j = 0; j < jmax; ++j) {               // wave-uniform trips
        const float4 x = y4[j];                      // wave-uniform bcast
        float s;
        s = fmaf(cc, s1, x.x - s2); s2 = s1; s1 = s;
        s = fmaf(cc, s1, x.y - s2); s2 = s1; s1 = s;
        s = fmaf(cc, s1, x.z - s2); s2 = s1; s1 = s;
        s = fmaf(cc, s1, x.w - s2); s2 = s1; s1 = s;
      }
      mx = fmaxf(mx, fmaf(s1, s1, fmaf(s2, s2, -(cc * s1 * s2))));
    }

    #pragma unroll
    for (int d = 32; d > 0; d >>= 1) mx = fmaxf(mx, __shfl_xor(mx, d));
    if (lane == 0) ws[f * 64 + bb] = mx;             // per-signal result
  }
}

// ---------------------------------------------------------------------------
// Kernel 2: EXACT R12 k_write (17.05us, 7.9 TB/s = 98% peak, proven R16).
// ---------------------------------------------------------------------------
__global__ __launch_bounds__(256) void k_write(const float* __restrict__ Q,
                                               const float* __restrict__ fc,
                                               const float* __restrict__ ws,
                                               float* __restrict__ out) {
  const int tid  = threadIdx.x;
  const int w    = tid >> 6;            // wave = row within the 4-row block
  const int lane = tid & 63;
  const int sig  = blockIdx.x * 4 + w;  // bb*512 + f
  const int f    = sig & 511;
  const int bb   = sig >> 9;

  float mx = ws[f * 64 + lane];         // 64 consecutive floats, coalesced
  #pragma unroll
  for (int d = 32; d > 0; d >>= 1) mx = fmaxf(mx, __shfl_xor(mx, d));
  const float inv = rsqrtf(mx);

  const float fcv = fc[f];
  const float q   = Q[bb * 512 + f];
  const float bc  = (fcv / q) * BCOEF_K;
  const float fcn = fcv * INV_FS;
  const float nstar = 4.0f / bc;

  vf4* __restrict__ orow = (vf4*)out + (size_t)sig * 256;
  #pragma unroll
  for (int r = 0; r < 4; ++r) {
    const int qi = (r << 6) + lane;     // quad index within row, 0..255
    const int t0 = qi << 2;             // t of first element in quad
    vf4 v = {0.0f, 0.0f, 0.0f, 0.0f};
    // quad covers n = 1021-t0 .. 1024-t0; all dead iff smallest n > nstar
    if ((float)(1021 - t0) <= nstar) {
      const float n0 = (float)(1024 - t0);
      const float n1 = (float)(1023 - t0);
      const float n2 = (float)(1022 - t0);
      const float n3 = (float)(1021 - t0);
      v.x = fast_env(bc * n0) * fast_carrier(fcn, n0) * inv;
      v.y = fast_env(bc * n1) * fast_carrier(fcn, n1) * inv;
      v.z = fast_env(bc * n2) * fast_carrier(fcn, n2) * inv;
      v.w = fast_env(bc * n3) * fast_carrier(fcn, n3) * inv;
    }
    orow[qi] = v;                       // plain cached store, coalesced
  }
}

// ---------------------------------------------------------------------------
extern "C" void kernel_launch(void* const* d_in, const int* in_sizes, int n_in,
                              void* d_out, int out_size, void* d_ws, size_t ws_size,
                              hipStream_t stream) {
  const float* Q  = (const float*)d_in[0];   // [64, 512] f32
  const float* fc = (const float*)d_in[1];   // [512] f32
  float* out      = (float*)d_out;           // [64, 512, 1024] f32
  float* ws       = (float*)d_ws;            // [512*64] per-signal |X|^2 max

  k_maxfft3<<<2048,        256, 0, stream>>>(Q, fc, ws);
  k_write  <<<64 * 512 / 4, 256, 0, stream>>>(Q, fc, ws, out);
}

// Round 14
// 152.871 us; speedup vs baseline: 1.0265x; 1.0265x over previous
//
#include <hip/hip_runtime.h>

// Problem: BATCH=64, NFILT=512, T=1024, FFT over first 512 samples, 257 bins.
//   bc = (fc/Q)*0.5*sqrt(2pi)/FS ; n = t+1
//   y[b,f,t] = exp(-(bc*n)^2) * cos(2pi*fc/FS*n)
//   maxsq[f] = max_{b,k} |DFT_512(y[b,f,0:512])[k]|^2
//   out[b,f,t] = y[b,f,1023-t] * rsqrt(maxsq[f])
//
// R24: R15's block-per-filter fusion at FULL occupancy.
//   R23 post-mortem: consolidated static 2-kernel = 156.9 (worse than R19
//   151.3) => static serial-4 costs ~5.6us vs dynamic. Reverted.
//   R15 re-diagnosis: its fused block-per-filter (165.9) ran 512x512 =
//   16 waves/CU (HALF occupancy). Compute tolerates that (4 waves/SIMD
//   saturate issue) but the STORE stream doesn't: R16's 98%-peak write ran
//   at 32 waves/CU. R15's write phase likely ran ~60% peak => ~+13us.
//   Fix: 512 blocks x 1024 threads (16 waves) = 2 blocks/CU x 16 = 32
//   waves/CU, exactly resident, single cohort.
//   Structure (math EXACT R12, correctness proven by R15's pass):
//     wave v: compute signals bb=16j+v (j=0..3), R12 body -> smax[bb]
//             (pruned -> 0.0);  __syncthreads;
//     64-wide fmaxf reduce (same tree as k_write => bit-identical inv);
//     wave v: write rows bb=16j+v with R12 row formula.
//   Overlap: fully-pruned high-f blocks skip compute and start storing
//   ~1us in; heavy low-f blocks compute while others stream => write BW
//   hides under compute; no dispatch boundary, no drain-then-write.
//   No atomics, no cross-block sync, no workspace.
//   __launch_bounds__(1024,8): VGPR<=64 => 8 waves/SIMD residency holds.
//   LDS 16x2KB + 512B = 32.75KB; 2 blocks/CU = 65.5KB < 160KB.
//   Prediction: total 135-145us (kernel ~35-42). Neutral 148-155 =>
//   revert to R19 + close out. absmax must stay EXACTLY 0.0009765625.

#define BCOEF_K 7.8332133582218756e-05f  // 0.5*sqrt(2*pi)/16000
#define INV_FS  6.25e-05f                // 1/16000
#define TWO_PI  6.28318530717958647692f
#define PI_F    3.14159265358979323846f
#define SIGK_K  115.2309f                // sqrt(2)*512/(2*pi)
#define KAPPA   1.3f                     // pruning safety factor
#define FULL_FC 700.0f                   // below this fc, evaluate all 64 b

typedef float vf4 __attribute__((ext_vector_type(4)));

__device__ __forceinline__ float fast_carrier(float fcn, float n) {
  float rev = fcn * n;
  float fr  = rev - floorf(rev);
  return __cosf(TWO_PI * fr);
}
__device__ __forceinline__ float fast_env(float x) { return __expf(-x * x); }

// ---------------------------------------------------------------------------
// One block per filter f. 16 waves; wave v handles signals/rows bb = 16j+v.
// ---------------------------------------------------------------------------
__global__ __launch_bounds__(1024, 8) void k_filter(const float* __restrict__ Q,
                                                    const float* __restrict__ fc,
                                                    float* __restrict__ out) {
  const int tid  = threadIdx.x;
  const int v    = tid >> 6;           // wave 0..15
  const int lane = tid & 63;
  const int f    = blockIdx.x;         // filter 0..511

  __shared__ __align__(16) float ybuf[16][512];
  __shared__ float smax[64];
  __shared__ float qcol[64];

  // one gather per block: the Q column for f (same values as R12's gather)
  if (tid < 64) qcol[tid] = Q[tid * 512 + f];
  __syncthreads();

  const float fcv = fc[f];
  const float fcn = fcv * INV_FS;

  // batch-max Q for the pruning predicate (same shfl tree as R12)
  float qq = qcol[lane];
  #pragma unroll
  for (int d = 32; d > 0; d >>= 1) qq = fmaxf(qq, __shfl_xor(qq, d));
  const float prthr = KAPPA * fcv * BCOEF_K;

  float* const yw = &ybuf[v][0];            // wave-private LDS row
  const float4* const y4 = (const float4*)yw;

  // ---------------- compute phase: 4 signals per wave ----------------
  for (int j = 0; j < 4; ++j) {
    const int   bb = (j << 4) + v;
    const float qv = qcol[bb];
    const float bc = (fcv / qv) * BCOEF_K;
    float mx = 0.0f;

    if (!(fcv >= FULL_FC && bc * qq > prthr)) {      // survivor
      // effective length: env < e^-16 beyond nstar = 4/bc (wave-uniform)
      const float nstar = 4.0f / bc;
      const int   N_eff = (nstar >= 510.0f) ? 512 : ((int)nstar + 2);
      const int   jmax  = (N_eff + 3) >> 2;          // float4 Goertzel groups
      const int   n4    = jmax << 2;                 // samples to generate

      // previous slot's LDS reads must drain before overwrite (wave-local)
      asm volatile("s_waitcnt lgkmcnt(0)" ::: "memory");

      // lane-strided generation
      const int nit_g = (n4 + 63) >> 6;              // 1..8, wave-uniform
      for (int r = 0; r < nit_g; ++r) {
        const int idx = (r << 6) + lane;             // t index; n = idx+1
        const float n = (float)(idx + 1);
        const float val = fast_env(bc * n) * fast_carrier(fcn, n);
        if (idx < n4) yw[idx] = val;                 // masked tail store
      }
      asm volatile("s_waitcnt lgkmcnt(0)" ::: "memory");

      // spectral-peak window (wave-uniform)
      const int kci  = (int)(fcn * 512.0f + 0.5f);
      const int W    = (int)(2.0f * (bc * SIGK_K)) + 6;
      const int k_lo = max(0, kci - W);
      const int k_hi = min(256, kci + W);
      const int nit  = ((k_hi - k_lo) >> 6) + 1;     // 1..5 iterations

      for (int it = 0; it < nit; ++it) {             // wave-uniform trips
        const int   kb = min(k_lo + (it << 6) + lane, k_hi);  // dup harmless
        const float cc = 2.0f * cosf((float)kb * (PI_F / 256.0f));
        float s1 = 0.0f, s2 = 0.0f;
        #pragma unroll 4
        for (int jj = 0; jj < jmax; ++jj) {          // wave-uniform trips
          const float4 x = y4[jj];                   // wave-uniform bcast
          float s;
          s = fmaf(cc, s1, x.x - s2); s2 = s1; s1 = s;
          s = fmaf(cc, s1, x.y - s2); s2 = s1; s1 = s;
          s = fmaf(cc, s1, x.z - s2); s2 = s1; s1 = s;
          s = fmaf(cc, s1, x.w - s2); s2 = s1; s1 = s;
        }
        mx = fmaxf(mx, fmaf(s1, s1, fmaf(s2, s2, -(cc * s1 * s2))));
      }
      #pragma unroll
      for (int d = 32; d > 0; d >>= 1) mx = fmaxf(mx, __shfl_xor(mx, d));
    }
    if (lane == 0) smax[bb] = mx;                    // pruned -> 0.0
  }

  __syncthreads();

  // ---------------- block max -> inv (same tree as k_write) --------------
  float mxall = smax[lane];
  #pragma unroll
  for (int d = 32; d > 0; d >>= 1) mxall = fmaxf(mxall, __shfl_xor(mxall, d));
  const float inv = rsqrtf(mxall);

  // ---------------- write phase: 4 rows per wave (exact R12 formula) -----
  for (int j = 0; j < 4; ++j) {
    const int   bb = (j << 4) + v;
    const float qv = qcol[bb];                       // == Q[bb*512+f]
    const float bc = (fcv / qv) * BCOEF_K;
    const float ns = 4.0f / bc;
    vf4* __restrict__ orow = (vf4*)out + (size_t)(bb * 512 + f) * 256;
    #pragma unroll
    for (int r = 0; r < 4; ++r) {
      const int qi = (r << 6) + lane;                // quad index 0..255
      const int t0 = qi << 2;                        // t of first element
      vf4 val = {0.0f, 0.0f, 0.0f, 0.0f};
      // quad covers n = 1021-t0 .. 1024-t0; dead iff smallest n > nstar
      if ((float)(1021 - t0) <= ns) {
        const float n0 = (float)(1024 - t0);
        const float n1 = (float)(1023 - t0);
        const float n2 = (float)(1022 - t0);
        const float n3 = (float)(1021 - t0);
        val.x = fast_env(bc * n0) * fast_carrier(fcn, n0) * inv;
        val.y = fast_env(bc * n1) * fast_carrier(fcn, n1) * inv;
        val.z = fast_env(bc * n2) * fast_carrier(fcn, n2) * inv;
        val.w = fast_env(bc * n3) * fast_carrier(fcn, n3) * inv;
      }
      orow[qi] = val;                                // coalesced cached store
    }
  }
}

// ---------------------------------------------------------------------------
extern "C" void kernel_launch(void* const* d_in, const int* in_sizes, int n_in,
                              void* d_out, int out_size, void* d_ws, size_t ws_size,
                              hipStream_t stream) {
  const float* Q  = (const float*)d_in[0];   // [64, 512] f32
  const float* fc = (const float*)d_in[1];   // [512] f32
  float* out      = (float*)d_out;           // [64, 512, 1024] f32
  (void)d_ws; (void)ws_size;                 // no workspace needed

  k_filter<<<512, 1024, 0, stream>>>(Q, fc, out);
}